// Round 4
// baseline (459.498 us; speedup 1.0000x reference)
//
#include <hip/hip_runtime.h>
#include <hip/hip_bf16.h>
#include <math.h>

#define B_SZ 8
#define L_SZ 1024
#define S_SZ 1000
#define DM   1024      // d_model = H*E = q/k/v row stride
#define DL   4096      // d_llm
#define NH   16
#define EH   64
#define QK_SCALE 0.180336880f   // (1/sqrt(64)) * log2(e): folded into Q projection
#define NTILES 32               // K-slice 1024 / BK 32

typedef __bf16 bf16x8 __attribute__((ext_vector_type(8)));
typedef __bf16 bf16x4 __attribute__((ext_vector_type(4)));
typedef float  f32x4  __attribute__((ext_vector_type(4)));

// async 16-byte global -> LDS (DMA, no VGPR round trip)
__device__ __forceinline__ void async16(const void* g, void* l) {
    __builtin_amdgcn_global_load_lds(
        (const __attribute__((address_space(1))) void*)g,
        (__attribute__((address_space(3))) void*)l, 16, 0, 0);
}

// ---------------------------------------------------------------------------
// fused prep: casts (bid<16192) + weight transposes (bid>=16192)
// ---------------------------------------------------------------------------
__global__ __launch_bounds__(256) void prep_kernel(
    const float* __restrict__ target, const float* __restrict__ source,
    const float* __restrict__ value,
    const float* __restrict__ Wq, const float* __restrict__ Wk,
    const float* __restrict__ Wv, const float* __restrict__ Wo,
    __bf16* __restrict__ Tb, __bf16* __restrict__ Sb, __bf16* __restrict__ Vb,
    __bf16* __restrict__ WqT, __bf16* __restrict__ WkT,
    __bf16* __restrict__ WvT, __bf16* __restrict__ WoT)
{
    __shared__ float t[64][68];
    int bid = blockIdx.x;
    if (bid < 16192) {
        const float* in; __bf16* out; int i;
        if (bid < 8192)       { in = target; out = Tb; i = bid * 256 + threadIdx.x; }
        else if (bid < 12192) { in = source; out = Sb; i = (bid - 8192)  * 256 + threadIdx.x; }
        else                  { in = value;  out = Vb; i = (bid - 12192) * 256 + threadIdx.x; }
        float4 x = ((const float4*)in)[i];
        bf16x4 y;
        y.x = (__bf16)x.x; y.y = (__bf16)x.y;
        y.z = (__bf16)x.z; y.w = (__bf16)x.w;
        ((bf16x4*)out)[i] = y;
        return;
    }
    bid -= 16192;
    const float* W; __bf16* WT; int K, N, bx, by;
    if (bid < 256)       { W = Wq; WT = WqT; K = DM; N = DM; int u = bid;        bx = u & 15; by = u >> 4; }
    else if (bid < 1280) { W = Wk; WT = WkT; K = DL; N = DM; int u = bid - 256;  bx = u & 15; by = u >> 4; }
    else if (bid < 2304) { W = Wv; WT = WvT; K = DL; N = DM; int u = bid - 1280; bx = u & 15; by = u >> 4; }
    else                 { W = Wo; WT = WoT; K = DM; N = DL; int u = bid - 2304; bx = u & 63; by = u >> 6; }
    const int k0 = by * 64, n0 = bx * 64;
    const int tx = threadIdx.x & 15, ty = threadIdx.x >> 4;

#pragma unroll
    for (int tt = 0; tt < 4; ++tt) {
        int r = ty + 16 * tt;
        float4 x = *(const float4*)&W[(size_t)(k0 + r) * N + n0 + 4 * tx];
        *(float4*)&t[r][4 * tx] = x;
    }
    __syncthreads();
#pragma unroll
    for (int tt = 0; tt < 4; ++tt) {
        int n = ty + 16 * tt;
        bf16x4 y;
        y.x = (__bf16)t[4 * tx + 0][n];
        y.y = (__bf16)t[4 * tx + 1][n];
        y.z = (__bf16)t[4 * tx + 2][n];
        y.w = (__bf16)t[4 * tx + 3][n];
        *(bf16x4*)&WT[(size_t)(n0 + n) * K + k0 + 4 * tx] = y;
    }
}

// ---------------------------------------------------------------------------
// Register-pipelined 256x256 GEMM body. BK=32, 512 thr = 8 waves (2M x 4N).
// 4 LDS slots (128 KB): phase t computes tile t from REGISTER frags (loaded
// last phase), ds_reads tile t+1's frags (slot landed at prev boundary),
// stages tile t+3. Boundary = vmcnt(4) [drain stage t+2] + lgkmcnt(0) +
// s_barrier. MFMA and LDS pipes overlap fully; zero lgkm wait before MFMAs.
// Race: slot (t+3)&3's last frag-reads finished 2 barriers before restage.
// vmcnt ledger (4 loads/wave per stage): prologue 12 -> vmcnt(4) lands
// slots 0,1; steady state 8 -> vmcnt(4) lands t+2, keeps t+3 in flight.
// omode 0: bf16 (acc+bias)*oscale | 1: f32 acc+bias | 2: f32 raw (split-K).
// ---------------------------------------------------------------------------
__device__ __forceinline__ void pipe_body(
    const __bf16* __restrict__ A, const __bf16* __restrict__ BT, int ld,
    const float* __restrict__ bias, void* __restrict__ Cv, int ldc,
    int M, int m0, int n0, float oscale, int omode,
    __bf16 (*sA)[256 * 32], __bf16 (*sB)[256 * 32])
{
    const int tid  = threadIdx.x;
    const int lane = tid & 63, wave = tid >> 6;
    const int wr = wave >> 2, wc = wave & 3;
    const int lm = lane & 15, lq = lane >> 4;

    f32x4 acc[8][4];
#pragma unroll
    for (int i = 0; i < 8; ++i)
#pragma unroll
        for (int j = 0; j < 4; ++j)
            acc[i][j] = (f32x4){0.f, 0.f, 0.f, 0.f};

    auto stage = [&](int slot, int t) {
        const int k0 = t * 32;
#pragma unroll
        for (int i = 0; i < 2; ++i) {
            int cc = i * 512 + tid;                // 16B chunk: row r, seg
            int r  = cc >> 2;
            int sg = (cc & 3) ^ ((r >> 1) & 3);    // pre-swizzled source seg
            int gm = m0 + r; if (gm >= M) gm = M - 1;
            async16(A  + (size_t)gm * ld + k0 + sg * 8,
                    (char*)sA[slot] + cc * 16);
            async16(BT + (size_t)(n0 + r) * ld + k0 + sg * 8,
                    (char*)sB[slot] + cc * 16);
        }
    };

    bf16x8 fa0[8], fb0[4], fa1[8], fb1[4];

    auto read_frags = [&](int slot, bf16x8 (&fa)[8], bf16x8 (&fb)[4]) {
#pragma unroll
        for (int ni = 0; ni < 4; ++ni) {
            int rr = wc * 64 + ni * 16 + lm;
            fb[ni] = *(const bf16x8*)((const char*)sB[slot]
                     + rr * 64 + ((lq ^ ((rr >> 1) & 3)) * 16));
        }
#pragma unroll
        for (int mi = 0; mi < 8; ++mi) {
            int rr = wr * 128 + mi * 16 + lm;
            fa[mi] = *(const bf16x8*)((const char*)sA[slot]
                     + rr * 64 + ((lq ^ ((rr >> 1) & 3)) * 16));
        }
    };

    auto mfma_all = [&](bf16x8 (&fa)[8], bf16x8 (&fb)[4]) {
        __builtin_amdgcn_s_setprio(1);
#pragma unroll
        for (int mi = 0; mi < 8; ++mi)
#pragma unroll
            for (int ni = 0; ni < 4; ++ni)
                acc[mi][ni] = __builtin_amdgcn_mfma_f32_16x16x32_bf16(
                    fa[mi], fb[ni], acc[mi][ni], 0, 0, 0);
        __builtin_amdgcn_s_setprio(0);
    };

    // prologue: tiles 0,1,2 in flight; land 0,1; read frags(0)
    stage(0, 0); stage(1, 1); stage(2, 2);
    asm volatile("s_waitcnt vmcnt(4)" ::: "memory");
    __builtin_amdgcn_s_barrier();
    __builtin_amdgcn_sched_barrier(0);
    read_frags(0, fa0, fb0);

    for (int tt = 0; tt < NTILES; tt += 2) {
        // phase tt: compute set0 (tile tt), prefetch frags(tt+1) -> set1
        if (tt + 3 < NTILES) stage((tt + 3) & 3, tt + 3);
        read_frags((tt + 1) & 3, fa1, fb1);
        mfma_all(fa0, fb0);
        if (tt + 3 < NTILES)
            asm volatile("s_waitcnt vmcnt(4)" ::: "memory");
        else
            asm volatile("s_waitcnt vmcnt(0)" ::: "memory");
        asm volatile("s_waitcnt lgkmcnt(0)" ::: "memory");
        __builtin_amdgcn_sched_barrier(0);
        __builtin_amdgcn_s_barrier();
        __builtin_amdgcn_sched_barrier(0);

        // phase tt+1: compute set1 (tile tt+1), prefetch frags(tt+2) -> set0
        if (tt + 4 < NTILES) stage((tt + 4) & 3, tt + 4);
        if (tt + 2 < NTILES) read_frags((tt + 2) & 3, fa0, fb0);
        mfma_all(fa1, fb1);
        if (tt + 2 < NTILES) {
            if (tt + 4 < NTILES)
                asm volatile("s_waitcnt vmcnt(4)" ::: "memory");
            else
                asm volatile("s_waitcnt vmcnt(0)" ::: "memory");
            asm volatile("s_waitcnt lgkmcnt(0)" ::: "memory");
            __builtin_amdgcn_sched_barrier(0);
            __builtin_amdgcn_s_barrier();
            __builtin_amdgcn_sched_barrier(0);
        }
    }

    // epilogue
#pragma unroll
    for (int mi = 0; mi < 8; ++mi) {
        int gm0 = m0 + wr * 128 + mi * 16 + lq * 4;
#pragma unroll
        for (int ni = 0; ni < 4; ++ni) {
            int gn = n0 + wc * 64 + ni * 16 + lm;
            float bv = (omode == 2) ? 0.f : bias[gn];
#pragma unroll
            for (int r = 0; r < 4; ++r) {
                int gm = gm0 + r;
                if (gm < M) {
                    float val = acc[mi][ni][r] + bv;
                    if (omode == 0)
                        ((__bf16*)Cv)[(size_t)gm * ldc + gn] = (__bf16)(val * oscale);
                    else
                        ((float*)Cv)[(size_t)gm * ldc + gn] = val;
                }
            }
        }
    }
}

// ---------------------------------------------------------------------------
// fused Q/K/V projection: 256 blocks, one wave-round, uniform Kslice=1024.
//  bid [0,128):   Q   (M=8192, 32x4 tiles)          -> qb   (bf16, QK_SCALE)
//  bid [128,192): K   split-K x4, 4x4 tiles, M=1000 -> kpart (f32 raw)
//  bid [192,256): V   split-K x4                    -> vpart (f32 raw)
// ---------------------------------------------------------------------------
__global__ __launch_bounds__(512, 2) void qkv_pipe_kernel(
    const __bf16* __restrict__ Tb, const __bf16* __restrict__ Sb,
    const __bf16* __restrict__ Vb,
    const __bf16* __restrict__ WqT, const __bf16* __restrict__ WkT,
    const __bf16* __restrict__ WvT,
    const float* __restrict__ bq,
    __bf16* __restrict__ qb, float* __restrict__ kpart, float* __restrict__ vpart)
{
    __shared__ __bf16 sA[4][256 * 32];
    __shared__ __bf16 sB[4][256 * 32];
    int bid = blockIdx.x;
    const __bf16 *A, *BT; const float* bias; void* Cv;
    int ld, M, m0, n0, omode; float osc;
    if (bid < 128) {
        A = Tb; BT = WqT; bias = bq; Cv = qb; ld = DM; M = B_SZ * L_SZ;
        m0 = (bid >> 2) * 256; n0 = (bid & 3) * 256; omode = 0; osc = QK_SCALE;
    } else if (bid < 192) {
        int u = bid - 128, ks = u >> 4, v = u & 15;
        A = Sb + ks * 1024; BT = WkT + ks * 1024; bias = nullptr;
        Cv = kpart + (size_t)ks * 1024000; ld = DL; M = S_SZ;
        m0 = (v >> 2) * 256; n0 = (v & 3) * 256; omode = 2; osc = 1.f;
    } else {
        int u = bid - 192, ks = u >> 4, v = u & 15;
        A = Vb + ks * 1024; BT = WvT + ks * 1024; bias = nullptr;
        Cv = vpart + (size_t)ks * 1024000; ld = DL; M = S_SZ;
        m0 = (v >> 2) * 256; n0 = (v & 3) * 256; omode = 2; osc = 1.f;
    }
    pipe_body(A, BT, ld, bias, Cv, DM, M, m0, n0, osc, omode, sA, sB);
}

// ---------------------------------------------------------------------------
// O-projection: same pipe body, 512 blocks (2 rounds), f32 out + bias.
// ---------------------------------------------------------------------------
__global__ __launch_bounds__(512, 2) void gemm_o_pipe_kernel(
    const __bf16* __restrict__ ab, const __bf16* __restrict__ WoT,
    const float* __restrict__ bo, float* __restrict__ out)
{
    __shared__ __bf16 sA[4][256 * 32];
    __shared__ __bf16 sB[4][256 * 32];
    int bid = blockIdx.x;
    bid = (bid & 7) * 64 + (bid >> 3);             // XCD swizzle (512%8==0)
    pipe_body(ab, WoT, DM, bo, out, DL, B_SZ * L_SZ,
              (bid >> 4) * 256, (bid & 15) * 256, 1.f, 1, sA, sB);
}

// ---------------------------------------------------------------------------
// split-K combine:
//  bid [0,1000): kb[s][d] = bf16(sum_j kpart[j] + bk)           (elementwise)
//  bid [1000,1256): vtb[d][s] = bf16(sum_j vpart[j] + bv), transposed 64x64
//                   tile, zero-padded for s >= 1000.
// ---------------------------------------------------------------------------
__global__ __launch_bounds__(256) void combine_kv_kernel(
    const float* __restrict__ kpart, const float* __restrict__ vpart,
    const float* __restrict__ bk, const float* __restrict__ bv,
    __bf16* __restrict__ kb, __bf16* __restrict__ vtb)
{
    __shared__ float t[64][68];
    const int bid = blockIdx.x, tid = threadIdx.x;
    if (bid < 1000) {
        int e4 = bid * 256 + tid;
        int col = (e4 & 255) * 4;
        float4 s = *(const float4*)&bk[col];
#pragma unroll
        for (int j = 0; j < 4; ++j) {
            float4 pp = *(const float4*)&kpart[(size_t)j * 1024000 + (size_t)e4 * 4];
            s.x += pp.x; s.y += pp.y; s.z += pp.z; s.w += pp.w;
        }
        bf16x4 y;
        y.x = (__bf16)s.x; y.y = (__bf16)s.y;
        y.z = (__bf16)s.z; y.w = (__bf16)s.w;
        ((bf16x4*)kb)[e4] = y;
    } else {
        int u = bid - 1000;
        int d0 = (u & 15) * 64, s0 = (u >> 4) * 64;
#pragma unroll
        for (int tt = 0; tt < 4; ++tt) {
            int idx = tt * 256 + tid;
            int r = idx >> 4, c4 = idx & 15;
            float4 s = {0.f, 0.f, 0.f, 0.f};
            if (s0 + r < S_SZ) {
                s = *(const float4*)&bv[d0 + c4 * 4];
#pragma unroll
                for (int j = 0; j < 4; ++j) {
                    float4 pp = *(const float4*)&vpart[(size_t)j * 1024000
                                + (size_t)(s0 + r) * 1024 + d0 + c4 * 4];
                    s.x += pp.x; s.y += pp.y; s.z += pp.z; s.w += pp.w;
                }
            }
            *(float4*)&t[r][c4 * 4] = s;
        }
        __syncthreads();
#pragma unroll
        for (int tt = 0; tt < 2; ++tt) {
            int idx = tt * 256 + tid;
            int d = idx >> 3, ch = idx & 7;
            bf16x8 o;
#pragma unroll
            for (int j = 0; j < 8; ++j) o[j] = (__bf16)t[ch * 8 + j][d];
            *(bf16x8*)&vtb[(size_t)(d0 + d) * 1024 + s0 + ch * 8] = o;
        }
    }
}

// ---------------------------------------------------------------------------
// MFMA flash attention (unchanged).
// ---------------------------------------------------------------------------
__global__ __launch_bounds__(256) void attn_mfma_kernel(
    const __bf16* __restrict__ q,   // (B*L, DM), pre-scaled
    const __bf16* __restrict__ k,   // (S, DM)
    const __bf16* __restrict__ vt,  // (DM, 1024) zero-padded s>=S
    __bf16* __restrict__ o)         // (B*L, DM)
{
    __shared__ __bf16 Ks [2][64 * 64];
    __shared__ __bf16 Vts[2][64 * 64];
    __shared__ __bf16 Ps [4][32 * 72];

    const int tid  = threadIdx.x;
    const int lane = tid & 63;
    const int wave = tid >> 6;
    const int lm   = lane & 15;
    const int lq   = lane >> 4;
    const int bh = blockIdx.y;
    const int b  = bh >> 4;
    const int h  = bh & 15;
    const int l0 = blockIdx.x * 128;
    const int row0 = b * L_SZ + l0 + wave * 32;

    bf16x8 qf[2][2];
#pragma unroll
    for (int mt = 0; mt < 2; ++mt)
#pragma unroll
        for (int ks = 0; ks < 2; ++ks)
            qf[mt][ks] = *(const bf16x8*)&q[(size_t)(row0 + mt * 16 + lm) * DM
                                           + h * 64 + ks * 32 + lq * 8];

    f32x4 oa[2][4];
    f32x4 lacc[2];
    float m_run[2][4];
#pragma unroll
    for (int mt = 0; mt < 2; ++mt) {
        lacc[mt] = (f32x4){0.f, 0.f, 0.f, 0.f};
#pragma unroll
        for (int r = 0; r < 4; ++r) m_run[mt][r] = -1e30f;
#pragma unroll
        for (int et = 0; et < 4; ++et) oa[mt][et] = (f32x4){0.f, 0.f, 0.f, 0.f};
    }

    bf16x8 vones;
#pragma unroll
    for (int j = 0; j < 8; ++j) vones[j] = (__bf16)1.0f;

    auto stage = [&](int bi, int s0v) {
#pragma unroll
        for (int t = 0; t < 2; ++t) {
            int cc = t * 256 + tid;
            int r = cc >> 3, segL = cc & 7;
            int segG = segL ^ (r & 7);
            int sg = s0v + r; if (sg >= S_SZ) sg = S_SZ - 1;
            async16(k  + (size_t)sg * DM + h * 64 + segG * 8,
                    (char*)Ks[bi] + cc * 16);
            async16(vt + (size_t)(h * 64 + r) * 1024 + s0v + segG * 8,
                    (char*)Vts[bi] + cc * 16);
        }
    };

    stage(0, 0);
    int cur = 0;

    for (int s0 = 0; s0 < S_SZ; s0 += 64) {
        __syncthreads();
        if (s0 + 64 < S_SZ) stage(cur ^ 1, s0 + 64);

        f32x4 sc[2][4];
#pragma unroll
        for (int mt = 0; mt < 2; ++mt)
#pragma unroll
            for (int nt = 0; nt < 4; ++nt)
                sc[mt][nt] = (f32x4){0.f, 0.f, 0.f, 0.f};
#pragma unroll
        for (int ks = 0; ks < 2; ++ks)
#pragma unroll
            for (int nt = 0; nt < 4; ++nt) {
                bf16x8 bK = *(const bf16x8*)((const char*)Ks[cur]
                    + (nt * 16 + lm) * 128 + (((ks * 4 + lq) ^ (lm & 7)) * 16));
#pragma unroll
                for (int mt = 0; mt < 2; ++mt)
                    sc[mt][nt] = __builtin_amdgcn_mfma_f32_16x16x32_bf16(
                        qf[mt][ks], bK, sc[mt][nt], 0, 0, 0);
            }

        if (s0 + 64 > S_SZ) {
#pragma unroll
            for (int nt = 0; nt < 4; ++nt) {
                bool masked = (s0 + nt * 16 + lm >= S_SZ);
                if (masked)
#pragma unroll
                    for (int mt = 0; mt < 2; ++mt)
#pragma unroll
                        for (int r = 0; r < 4; ++r) sc[mt][nt][r] = -1e30f;
            }
        }

        float pm[2][4];
        bool ok = true;
#pragma unroll
        for (int mt = 0; mt < 2; ++mt)
#pragma unroll
            for (int r = 0; r < 4; ++r) {
                pm[mt][r] = fmaxf(fmaxf(sc[mt][0][r], sc[mt][1][r]),
                                  fmaxf(sc[mt][2][r], sc[mt][3][r]));
                ok = ok && (pm[mt][r] <= m_run[mt][r] + 8.f);
            }
        if (!__all((int)ok)) {
#pragma unroll
            for (int mt = 0; mt < 2; ++mt)
#pragma unroll
                for (int r = 0; r < 4; ++r) {
                    float mx = pm[mt][r];
#pragma unroll
                    for (int off = 1; off < 16; off <<= 1)
                        mx = fmaxf(mx, __shfl_xor(mx, off));
                    float mnew  = fmaxf(m_run[mt][r], mx);
                    float alpha = __builtin_amdgcn_exp2f(m_run[mt][r] - mnew);
                    m_run[mt][r] = mnew;
                    lacc[mt][r] *= alpha;
#pragma unroll
                    for (int et = 0; et < 4; ++et)
                        oa[mt][et][r] *= alpha;
                }
        }

#pragma unroll
        for (int mt = 0; mt < 2; ++mt)
#pragma unroll
            for (int r = 0; r < 4; ++r) {
                int prow = (mt * 16 + lq * 4 + r) * 72;
#pragma unroll
                for (int nt = 0; nt < 4; ++nt) {
                    float pv = __builtin_amdgcn_exp2f(sc[mt][nt][r] - m_run[mt][r]);
                    Ps[wave][prow + nt * 16 + lm] = (__bf16)pv;
                }
            }

        asm volatile("s_waitcnt lgkmcnt(0)" ::: "memory");

#pragma unroll
        for (int ks = 0; ks < 2; ++ks) {
            bf16x8 aP[2];
#pragma unroll
            for (int mt = 0; mt < 2; ++mt)
                aP[mt] = *(const bf16x8*)&Ps[wave][(mt * 16 + lm) * 72
                                                  + ks * 32 + lq * 8];
#pragma unroll
            for (int mt = 0; mt < 2; ++mt)
                lacc[mt] = __builtin_amdgcn_mfma_f32_16x16x32_bf16(
                    aP[mt], vones, lacc[mt], 0, 0, 0);
#pragma unroll
            for (int et = 0; et < 4; ++et) {
                bf16x8 bV = *(const bf16x8*)((const char*)Vts[cur]
                    + (et * 16 + lm) * 128 + (((ks * 4 + lq) ^ (lm & 7)) * 16));
#pragma unroll
                for (int mt = 0; mt < 2; ++mt)
                    oa[mt][et] = __builtin_amdgcn_mfma_f32_16x16x32_bf16(
                        aP[mt], bV, oa[mt][et], 0, 0, 0);
            }
        }
        cur ^= 1;
    }

#pragma unroll
    for (int mt = 0; mt < 2; ++mt)
#pragma unroll
        for (int r = 0; r < 4; ++r) {
            float inv = 1.f / lacc[mt][r];
            size_t rowi = (size_t)(row0 + mt * 16 + lq * 4 + r) * DM + h * 64;
#pragma unroll
            for (int et = 0; et < 4; ++et)
                o[rowi + et * 16 + lm] = (__bf16)(oa[mt][et][r] * inv);
        }
}

// ---------------------------------------------------------------------------
extern "C" void kernel_launch(void* const* d_in, const int* in_sizes, int n_in,
                              void* d_out, int out_size, void* d_ws, size_t ws_size,
                              hipStream_t stream)
{
    const float* target = (const float*)d_in[0];
    const float* source = (const float*)d_in[1];
    const float* value  = (const float*)d_in[2];
    const float* Wq = (const float*)d_in[3];
    const float* bq = (const float*)d_in[4];
    const float* Wk = (const float*)d_in[5];
    const float* bk = (const float*)d_in[6];
    const float* Wv = (const float*)d_in[7];
    const float* bv = (const float*)d_in[8];
    const float* Wo = (const float*)d_in[9];
    const float* bo = (const float*)d_in[10];
    float* out = (float*)d_out;

    // ws layout (bytes):
    char* p = (char*)d_ws;
    __bf16* Tb  = (__bf16*)(p);              // target bf16   16,777,216 [ab alias]
    __bf16* Sb  = (__bf16*)(p + 16777216);   // source bf16    8,192,000
    __bf16* vtb = (__bf16*)(p + 16777216);   // V^T bf16 2,097,152 (aliases Sb,
                                             //  written by combine after QKV done)
    __bf16* kb  = (__bf16*)(p + 24969216);   // K proj bf16    2,048,000
    __bf16* WqT = (__bf16*)(p + 29065216);   // Wq^T bf16      2,097,152
    __bf16* WoT = (__bf16*)(p + 31162368);   // Wo^T bf16      8,388,608
    char*   R   =           p + 39550976;    // region 24,969,216
    __bf16* Vb  = (__bf16*)(R);              // value bf16     8,192,000
    __bf16* WvT = (__bf16*)(R + 8192000);    // Wv^T bf16      8,388,608
    __bf16* WkT = (__bf16*)(R + 16580608);   // Wk^T bf16      8,388,608
    // d_out (134 MB) doubles as scratch until the final O-proj overwrites it:
    __bf16* qb    = (__bf16*)d_out;                       // 16,777,216
    float*  kpart = (float*)((char*)d_out + 16777216);    // 4x1000x1024 f32 16,384,000
    float*  vpart = (float*)((char*)d_out + 33161216);    // 16,384,000
    __bf16* ab    = (__bf16*)(p);            // attn out (aliases Tb, dead by then)

    // 1. fused prep: casts + weight transposes (16192 + 3328 blocks)
    prep_kernel<<<19520, 256, 0, stream>>>(target, source, value, Wq, Wk, Wv, Wo,
                                           Tb, Sb, Vb, WqT, WkT, WvT, WoT);
    // 2. fused Q/K/V projections: 256 uniform pipelined blocks, one round
    qkv_pipe_kernel<<<256, 512, 0, stream>>>(Tb, Sb, Vb, WqT, WkT, WvT,
                                             bq, qb, kpart, vpart);
    // 3. split-K combine: kb elementwise; vtb transposed+padded
    combine_kv_kernel<<<1256, 256, 0, stream>>>(kpart, vpart, bk, bv, kb, vtb);
    // 4. MFMA flash attention
    attn_mfma_kernel<<<dim3(8, 128), 256, 0, stream>>>(qb, kb, vtb, ab);
    // 5. output projection: register-pipelined 256^2 kernel
    gemm_o_pipe_kernel<<<512, 512, 0, stream>>>(ab, WoT, bo, out);
}

// Round 5
// 458.846 us; speedup vs baseline: 1.0014x; 1.0014x over previous
//
#include <hip/hip_runtime.h>
#include <hip/hip_bf16.h>
#include <math.h>

#define B_SZ 8
#define L_SZ 1024
#define S_SZ 1000
#define DM   1024      // d_model = H*E = q/k/v row stride
#define DL   4096      // d_llm
#define NH   16
#define EH   64
#define QK_SCALE 0.180336880f   // (1/sqrt(64)) * log2(e): folded into Q projection
#define NTILES 32               // K-slice 1024 / BK 32

typedef __bf16 bf16x8 __attribute__((ext_vector_type(8)));
typedef __bf16 bf16x4 __attribute__((ext_vector_type(4)));
typedef float  f32x4  __attribute__((ext_vector_type(4)));

// async 16-byte global -> LDS (DMA, no VGPR round trip)
__device__ __forceinline__ void async16(const void* g, void* l) {
    __builtin_amdgcn_global_load_lds(
        (const __attribute__((address_space(1))) void*)g,
        (__attribute__((address_space(3))) void*)l, 16, 0, 0);
}

// ---------------------------------------------------------------------------
// fused prep: casts (bid<16192) + weight transposes (bid>=16192)
// ---------------------------------------------------------------------------
__global__ __launch_bounds__(256) void prep_kernel(
    const float* __restrict__ target, const float* __restrict__ source,
    const float* __restrict__ value,
    const float* __restrict__ Wq, const float* __restrict__ Wk,
    const float* __restrict__ Wv, const float* __restrict__ Wo,
    __bf16* __restrict__ Tb, __bf16* __restrict__ Sb, __bf16* __restrict__ Vb,
    __bf16* __restrict__ WqT, __bf16* __restrict__ WkT,
    __bf16* __restrict__ WvT, __bf16* __restrict__ WoT)
{
    __shared__ float t[64][68];
    int bid = blockIdx.x;
    if (bid < 16192) {
        const float* in; __bf16* out; int i;
        if (bid < 8192)       { in = target; out = Tb; i = bid * 256 + threadIdx.x; }
        else if (bid < 12192) { in = source; out = Sb; i = (bid - 8192)  * 256 + threadIdx.x; }
        else                  { in = value;  out = Vb; i = (bid - 12192) * 256 + threadIdx.x; }
        float4 x = ((const float4*)in)[i];
        bf16x4 y;
        y.x = (__bf16)x.x; y.y = (__bf16)x.y;
        y.z = (__bf16)x.z; y.w = (__bf16)x.w;
        ((bf16x4*)out)[i] = y;
        return;
    }
    bid -= 16192;
    const float* W; __bf16* WT; int K, N, bx, by;
    if (bid < 256)       { W = Wq; WT = WqT; K = DM; N = DM; int u = bid;        bx = u & 15; by = u >> 4; }
    else if (bid < 1280) { W = Wk; WT = WkT; K = DL; N = DM; int u = bid - 256;  bx = u & 15; by = u >> 4; }
    else if (bid < 2304) { W = Wv; WT = WvT; K = DL; N = DM; int u = bid - 1280; bx = u & 15; by = u >> 4; }
    else                 { W = Wo; WT = WoT; K = DM; N = DL; int u = bid - 2304; bx = u & 63; by = u >> 6; }
    const int k0 = by * 64, n0 = bx * 64;
    const int tx = threadIdx.x & 15, ty = threadIdx.x >> 4;

#pragma unroll
    for (int tt = 0; tt < 4; ++tt) {
        int r = ty + 16 * tt;
        float4 x = *(const float4*)&W[(size_t)(k0 + r) * N + n0 + 4 * tx];
        *(float4*)&t[r][4 * tx] = x;
    }
    __syncthreads();
#pragma unroll
    for (int tt = 0; tt < 4; ++tt) {
        int n = ty + 16 * tt;
        bf16x4 y;
        y.x = (__bf16)t[4 * tx + 0][n];
        y.y = (__bf16)t[4 * tx + 1][n];
        y.z = (__bf16)t[4 * tx + 2][n];
        y.w = (__bf16)t[4 * tx + 3][n];
        *(bf16x4*)&WT[(size_t)(n0 + n) * K + k0 + 4 * tx] = y;
    }
}

// ---------------------------------------------------------------------------
// Fine-phase register-pipelined 256x256 GEMM body. BK=32, 512 thr = 8 waves
// (2M x 4N). 4 LDS slots (128 KB), tile t -> slot t&3.
// Per tile, TWO phases of 16 MFMA each (m201 rhythm). All ds_reads feed the
// NEXT tile's MFMAs (register-pipelined) so no phase waits on its own reads:
//   P0: stage(t+3,h0) | ds-read frags(t+1): fb[0-3]+fa[0-3] | MFMA(t) mi0-3
//       s_barrier
//   P1: stage(t+3,h1) | ds-read frags(t+1): fa[4-7]        | MFMA(t) mi4-7
//       boundary: vmcnt(4) [lands tile t+2, keeps t+3 in flight; never 0
//       mid-loop] + lgkmcnt(0) [frags(t+1), issued >=1 phase ago] + s_barrier
// Invariants (induction): entering tile t, frags(t) are in registers and
// slot(t+1) is landed-confirmed (vmcnt+barrier at t-1 boundary). stage(t+3)
// overwrites slot (t-1)&3, whose last reads (frags(t-1), issued during t-2)
// were lgkm-drained at t-2's boundary -- 3 barriers of separation.
// vmcnt ledger (4 loads/wave/tile, 2/half): prologue 12 -> vmcnt(8) lands
// tile0; steady boundary 8 -> vmcnt(4) lands t+2.
// omode 0: bf16 (acc+bias)*oscale | 1: f32 acc+bias | 2: f32 raw (split-K).
// ---------------------------------------------------------------------------
__device__ __forceinline__ void pipe_body(
    const __bf16* __restrict__ A, const __bf16* __restrict__ BT, int ld,
    const float* __restrict__ bias, void* __restrict__ Cv, int ldc,
    int M, int m0, int n0, float oscale, int omode,
    __bf16 (*sA)[256 * 32], __bf16 (*sB)[256 * 32])
{
    const int tid  = threadIdx.x;
    const int lane = tid & 63, wave = tid >> 6;
    const int wr = wave >> 2, wc = wave & 3;
    const int lm = lane & 15, lq = lane >> 4;

    f32x4 acc[8][4];
#pragma unroll
    for (int i = 0; i < 8; ++i)
#pragma unroll
        for (int j = 0; j < 4; ++j)
            acc[i][j] = (f32x4){0.f, 0.f, 0.f, 0.f};

    // one half-tile (rows h*128..h*128+127 of A and B): 2 async16 per thread
    auto stage_half = [&](int slot, int t, int h) {
        const int k0 = t * 32;
        int cc = h * 512 + tid;                // 16B chunk: row r, seg
        int r  = cc >> 2;
        int sg = (cc & 3) ^ ((r >> 1) & 3);    // pre-swizzled source seg
        int gm = m0 + r; if (gm >= M) gm = M - 1;
        async16(A  + (size_t)gm * ld + k0 + sg * 8, (char*)sA[slot] + cc * 16);
        async16(BT + (size_t)(n0 + r) * ld + k0 + sg * 8, (char*)sB[slot] + cc * 16);
    };

    bf16x8 fa0[8], fb0[4], fa1[8], fb1[4];

    auto read_fb = [&](int slot, bf16x8 (&fb)[4]) {
#pragma unroll
        for (int ni = 0; ni < 4; ++ni) {
            int rr = wc * 64 + ni * 16 + lm;
            fb[ni] = *(const bf16x8*)((const char*)sB[slot]
                     + rr * 64 + ((lq ^ ((rr >> 1) & 3)) * 16));
        }
    };
    auto read_fa_lo = [&](int slot, bf16x8 (&fa)[8]) {
#pragma unroll
        for (int mi = 0; mi < 4; ++mi) {
            int rr = wr * 128 + mi * 16 + lm;
            fa[mi] = *(const bf16x8*)((const char*)sA[slot]
                     + rr * 64 + ((lq ^ ((rr >> 1) & 3)) * 16));
        }
    };
    auto read_fa_hi = [&](int slot, bf16x8 (&fa)[8]) {
#pragma unroll
        for (int mi = 4; mi < 8; ++mi) {
            int rr = wr * 128 + mi * 16 + lm;
            fa[mi] = *(const bf16x8*)((const char*)sA[slot]
                     + rr * 64 + ((lq ^ ((rr >> 1) & 3)) * 16));
        }
    };
    auto mfma_lo = [&](bf16x8 (&fa)[8], bf16x8 (&fb)[4]) {
        __builtin_amdgcn_s_setprio(1);
#pragma unroll
        for (int mi = 0; mi < 4; ++mi)
#pragma unroll
            for (int ni = 0; ni < 4; ++ni)
                acc[mi][ni] = __builtin_amdgcn_mfma_f32_16x16x32_bf16(
                    fa[mi], fb[ni], acc[mi][ni], 0, 0, 0);
        __builtin_amdgcn_s_setprio(0);
    };
    auto mfma_hi = [&](bf16x8 (&fa)[8], bf16x8 (&fb)[4]) {
        __builtin_amdgcn_s_setprio(1);
#pragma unroll
        for (int mi = 4; mi < 8; ++mi)
#pragma unroll
            for (int ni = 0; ni < 4; ++ni)
                acc[mi][ni] = __builtin_amdgcn_mfma_f32_16x16x32_bf16(
                    fa[mi], fb[ni], acc[mi][ni], 0, 0, 0);
        __builtin_amdgcn_s_setprio(0);
    };

    // prologue: tiles 0,1,2 staged; land 0; frag-read(0); confirm tile 1
    stage_half(0, 0, 0); stage_half(0, 0, 1);
    stage_half(1, 1, 0); stage_half(1, 1, 1);
    stage_half(2, 2, 0); stage_half(2, 2, 1);
    asm volatile("s_waitcnt vmcnt(8)" ::: "memory");   // tile 0 landed
    __builtin_amdgcn_sched_barrier(0);
    __builtin_amdgcn_s_barrier();
    __builtin_amdgcn_sched_barrier(0);
    read_fb(0, fb0); read_fa_lo(0, fa0); read_fa_hi(0, fa0);
    asm volatile("s_waitcnt vmcnt(4)" ::: "memory");   // tile 1 landed
    asm volatile("s_waitcnt lgkmcnt(0)" ::: "memory"); // frags(0) in regs
    __builtin_amdgcn_sched_barrier(0);
    __builtin_amdgcn_s_barrier();
    __builtin_amdgcn_sched_barrier(0);

    for (int tt = 0; tt < NTILES; tt += 2) {
        // ================= tile tt (cur=set0, nxt=set1) =================
        // P0
        if (tt + 3 < NTILES) stage_half((tt + 3) & 3, tt + 3, 0);
        if (tt + 1 < NTILES) { read_fb((tt + 1) & 3, fb1); read_fa_lo((tt + 1) & 3, fa1); }
        mfma_lo(fa0, fb0);
        __builtin_amdgcn_s_barrier();
        // P1
        if (tt + 3 < NTILES) stage_half((tt + 3) & 3, tt + 3, 1);
        if (tt + 1 < NTILES) read_fa_hi((tt + 1) & 3, fa1);
        mfma_hi(fa0, fb0);
        if (tt + 1 < NTILES) {
            if (tt + 3 < NTILES)
                asm volatile("s_waitcnt vmcnt(4)" ::: "memory");
            else
                asm volatile("s_waitcnt vmcnt(0)" ::: "memory");
            asm volatile("s_waitcnt lgkmcnt(0)" ::: "memory");
            __builtin_amdgcn_sched_barrier(0);
            __builtin_amdgcn_s_barrier();
            __builtin_amdgcn_sched_barrier(0);
        }
        // ================= tile tt+1 (cur=set1, nxt=set0) ===============
        const int t1 = tt + 1;   // NTILES even -> always < NTILES
        // P0
        if (t1 + 3 < NTILES) stage_half((t1 + 3) & 3, t1 + 3, 0);
        if (t1 + 1 < NTILES) { read_fb((t1 + 1) & 3, fb0); read_fa_lo((t1 + 1) & 3, fa0); }
        mfma_lo(fa1, fb1);
        __builtin_amdgcn_s_barrier();
        // P1
        if (t1 + 3 < NTILES) stage_half((t1 + 3) & 3, t1 + 3, 1);
        if (t1 + 1 < NTILES) read_fa_hi((t1 + 1) & 3, fa0);
        mfma_hi(fa1, fb1);
        if (t1 + 1 < NTILES) {
            if (t1 + 3 < NTILES)
                asm volatile("s_waitcnt vmcnt(4)" ::: "memory");
            else
                asm volatile("s_waitcnt vmcnt(0)" ::: "memory");
            asm volatile("s_waitcnt lgkmcnt(0)" ::: "memory");
            __builtin_amdgcn_sched_barrier(0);
            __builtin_amdgcn_s_barrier();
            __builtin_amdgcn_sched_barrier(0);
        }
    }

    // epilogue
#pragma unroll
    for (int mi = 0; mi < 8; ++mi) {
        int gm0 = m0 + wr * 128 + mi * 16 + lq * 4;
#pragma unroll
        for (int ni = 0; ni < 4; ++ni) {
            int gn = n0 + wc * 64 + ni * 16 + lm;
            float bv = (omode == 2) ? 0.f : bias[gn];
#pragma unroll
            for (int r = 0; r < 4; ++r) {
                int gm = gm0 + r;
                if (gm < M) {
                    float val = acc[mi][ni][r] + bv;
                    if (omode == 0)
                        ((__bf16*)Cv)[(size_t)gm * ldc + gn] = (__bf16)(val * oscale);
                    else
                        ((float*)Cv)[(size_t)gm * ldc + gn] = val;
                }
            }
        }
    }
}

// ---------------------------------------------------------------------------
// fused Q/K/V projection: 256 blocks, one wave-round, uniform Kslice=1024.
//  bid [0,128):   Q   (M=8192, 32x4 tiles)          -> qb   (bf16, QK_SCALE)
//  bid [128,192): K   split-K x4, 4x4 tiles, M=1000 -> kpart (f32 raw)
//  bid [192,256): V   split-K x4                    -> vpart (f32 raw)
// ---------------------------------------------------------------------------
__global__ __launch_bounds__(512, 2) void qkv_pipe_kernel(
    const __bf16* __restrict__ Tb, const __bf16* __restrict__ Sb,
    const __bf16* __restrict__ Vb,
    const __bf16* __restrict__ WqT, const __bf16* __restrict__ WkT,
    const __bf16* __restrict__ WvT,
    const float* __restrict__ bq,
    __bf16* __restrict__ qb, float* __restrict__ kpart, float* __restrict__ vpart)
{
    __shared__ __bf16 sA[4][256 * 32];
    __shared__ __bf16 sB[4][256 * 32];
    int bid = blockIdx.x;
    const __bf16 *A, *BT; const float* bias; void* Cv;
    int ld, M, m0, n0, omode; float osc;
    if (bid < 128) {
        A = Tb; BT = WqT; bias = bq; Cv = qb; ld = DM; M = B_SZ * L_SZ;
        m0 = (bid >> 2) * 256; n0 = (bid & 3) * 256; omode = 0; osc = QK_SCALE;
    } else if (bid < 192) {
        int u = bid - 128, ks = u >> 4, v = u & 15;
        A = Sb + ks * 1024; BT = WkT + ks * 1024; bias = nullptr;
        Cv = kpart + (size_t)ks * 1024000; ld = DL; M = S_SZ;
        m0 = (v >> 2) * 256; n0 = (v & 3) * 256; omode = 2; osc = 1.f;
    } else {
        int u = bid - 192, ks = u >> 4, v = u & 15;
        A = Vb + ks * 1024; BT = WvT + ks * 1024; bias = nullptr;
        Cv = vpart + (size_t)ks * 1024000; ld = DL; M = S_SZ;
        m0 = (v >> 2) * 256; n0 = (v & 3) * 256; omode = 2; osc = 1.f;
    }
    pipe_body(A, BT, ld, bias, Cv, DM, M, m0, n0, osc, omode, sA, sB);
}

// ---------------------------------------------------------------------------
// O-projection: same pipe body, 512 blocks (2 rounds), f32 out + bias.
// ---------------------------------------------------------------------------
__global__ __launch_bounds__(512, 2) void gemm_o_pipe_kernel(
    const __bf16* __restrict__ ab, const __bf16* __restrict__ WoT,
    const float* __restrict__ bo, float* __restrict__ out)
{
    __shared__ __bf16 sA[4][256 * 32];
    __shared__ __bf16 sB[4][256 * 32];
    int bid = blockIdx.x;
    bid = (bid & 7) * 64 + (bid >> 3);             // XCD swizzle (512%8==0)
    pipe_body(ab, WoT, DM, bo, out, DL, B_SZ * L_SZ,
              (bid >> 4) * 256, (bid & 15) * 256, 1.f, 1, sA, sB);
}

// ---------------------------------------------------------------------------
// split-K combine:
//  bid [0,1000): kb[s][d] = bf16(sum_j kpart[j] + bk)           (elementwise)
//  bid [1000,1256): vtb[d][s] = bf16(sum_j vpart[j] + bv), transposed 64x64
//                   tile, zero-padded for s >= 1000.
// ---------------------------------------------------------------------------
__global__ __launch_bounds__(256) void combine_kv_kernel(
    const float* __restrict__ kpart, const float* __restrict__ vpart,
    const float* __restrict__ bk, const float* __restrict__ bv,
    __bf16* __restrict__ kb, __bf16* __restrict__ vtb)
{
    __shared__ float t[64][68];
    const int bid = blockIdx.x, tid = threadIdx.x;
    if (bid < 1000) {
        int e4 = bid * 256 + tid;
        int col = (e4 & 255) * 4;
        float4 s = *(const float4*)&bk[col];
#pragma unroll
        for (int j = 0; j < 4; ++j) {
            float4 pp = *(const float4*)&kpart[(size_t)j * 1024000 + (size_t)e4 * 4];
            s.x += pp.x; s.y += pp.y; s.z += pp.z; s.w += pp.w;
        }
        bf16x4 y;
        y.x = (__bf16)s.x; y.y = (__bf16)s.y;
        y.z = (__bf16)s.z; y.w = (__bf16)s.w;
        ((bf16x4*)kb)[e4] = y;
    } else {
        int u = bid - 1000;
        int d0 = (u & 15) * 64, s0 = (u >> 4) * 64;
#pragma unroll
        for (int tt = 0; tt < 4; ++tt) {
            int idx = tt * 256 + tid;
            int r = idx >> 4, c4 = idx & 15;
            float4 s = {0.f, 0.f, 0.f, 0.f};
            if (s0 + r < S_SZ) {
                s = *(const float4*)&bv[d0 + c4 * 4];
#pragma unroll
                for (int j = 0; j < 4; ++j) {
                    float4 pp = *(const float4*)&vpart[(size_t)j * 1024000
                                + (size_t)(s0 + r) * 1024 + d0 + c4 * 4];
                    s.x += pp.x; s.y += pp.y; s.z += pp.z; s.w += pp.w;
                }
            }
            *(float4*)&t[r][c4 * 4] = s;
        }
        __syncthreads();
#pragma unroll
        for (int tt = 0; tt < 2; ++tt) {
            int idx = tt * 256 + tid;
            int d = idx >> 3, ch = idx & 7;
            bf16x8 o;
#pragma unroll
            for (int j = 0; j < 8; ++j) o[j] = (__bf16)t[ch * 8 + j][d];
            *(bf16x8*)&vtb[(size_t)(d0 + d) * 1024 + s0 + ch * 8] = o;
        }
    }
}

// ---------------------------------------------------------------------------
// MFMA flash attention (unchanged).
// ---------------------------------------------------------------------------
__global__ __launch_bounds__(256) void attn_mfma_kernel(
    const __bf16* __restrict__ q,   // (B*L, DM), pre-scaled
    const __bf16* __restrict__ k,   // (S, DM)
    const __bf16* __restrict__ vt,  // (DM, 1024) zero-padded s>=S
    __bf16* __restrict__ o)         // (B*L, DM)
{
    __shared__ __bf16 Ks [2][64 * 64];
    __shared__ __bf16 Vts[2][64 * 64];
    __shared__ __bf16 Ps [4][32 * 72];

    const int tid  = threadIdx.x;
    const int lane = tid & 63;
    const int wave = tid >> 6;
    const int lm   = lane & 15;
    const int lq   = lane >> 4;
    const int bh = blockIdx.y;
    const int b  = bh >> 4;
    const int h  = bh & 15;
    const int l0 = blockIdx.x * 128;
    const int row0 = b * L_SZ + l0 + wave * 32;

    bf16x8 qf[2][2];
#pragma unroll
    for (int mt = 0; mt < 2; ++mt)
#pragma unroll
        for (int ks = 0; ks < 2; ++ks)
            qf[mt][ks] = *(const bf16x8*)&q[(size_t)(row0 + mt * 16 + lm) * DM
                                           + h * 64 + ks * 32 + lq * 8];

    f32x4 oa[2][4];
    f32x4 lacc[2];
    float m_run[2][4];
#pragma unroll
    for (int mt = 0; mt < 2; ++mt) {
        lacc[mt] = (f32x4){0.f, 0.f, 0.f, 0.f};
#pragma unroll
        for (int r = 0; r < 4; ++r) m_run[mt][r] = -1e30f;
#pragma unroll
        for (int et = 0; et < 4; ++et) oa[mt][et] = (f32x4){0.f, 0.f, 0.f, 0.f};
    }

    bf16x8 vones;
#pragma unroll
    for (int j = 0; j < 8; ++j) vones[j] = (__bf16)1.0f;

    auto stage = [&](int bi, int s0v) {
#pragma unroll
        for (int t = 0; t < 2; ++t) {
            int cc = t * 256 + tid;
            int r = cc >> 3, segL = cc & 7;
            int segG = segL ^ (r & 7);
            int sg = s0v + r; if (sg >= S_SZ) sg = S_SZ - 1;
            async16(k  + (size_t)sg * DM + h * 64 + segG * 8,
                    (char*)Ks[bi] + cc * 16);
            async16(vt + (size_t)(h * 64 + r) * 1024 + s0v + segG * 8,
                    (char*)Vts[bi] + cc * 16);
        }
    };

    stage(0, 0);
    int cur = 0;

    for (int s0 = 0; s0 < S_SZ; s0 += 64) {
        __syncthreads();
        if (s0 + 64 < S_SZ) stage(cur ^ 1, s0 + 64);

        f32x4 sc[2][4];
#pragma unroll
        for (int mt = 0; mt < 2; ++mt)
#pragma unroll
            for (int nt = 0; nt < 4; ++nt)
                sc[mt][nt] = (f32x4){0.f, 0.f, 0.f, 0.f};
#pragma unroll
        for (int ks = 0; ks < 2; ++ks)
#pragma unroll
            for (int nt = 0; nt < 4; ++nt) {
                bf16x8 bK = *(const bf16x8*)((const char*)Ks[cur]
                    + (nt * 16 + lm) * 128 + (((ks * 4 + lq) ^ (lm & 7)) * 16));
#pragma unroll
                for (int mt = 0; mt < 2; ++mt)
                    sc[mt][nt] = __builtin_amdgcn_mfma_f32_16x16x32_bf16(
                        qf[mt][ks], bK, sc[mt][nt], 0, 0, 0);
            }

        if (s0 + 64 > S_SZ) {
#pragma unroll
            for (int nt = 0; nt < 4; ++nt) {
                bool masked = (s0 + nt * 16 + lm >= S_SZ);
                if (masked)
#pragma unroll
                    for (int mt = 0; mt < 2; ++mt)
#pragma unroll
                        for (int r = 0; r < 4; ++r) sc[mt][nt][r] = -1e30f;
            }
        }

        float pm[2][4];
        bool ok = true;
#pragma unroll
        for (int mt = 0; mt < 2; ++mt)
#pragma unroll
            for (int r = 0; r < 4; ++r) {
                pm[mt][r] = fmaxf(fmaxf(sc[mt][0][r], sc[mt][1][r]),
                                  fmaxf(sc[mt][2][r], sc[mt][3][r]));
                ok = ok && (pm[mt][r] <= m_run[mt][r] + 8.f);
            }
        if (!__all((int)ok)) {
#pragma unroll
            for (int mt = 0; mt < 2; ++mt)
#pragma unroll
                for (int r = 0; r < 4; ++r) {
                    float mx = pm[mt][r];
#pragma unroll
                    for (int off = 1; off < 16; off <<= 1)
                        mx = fmaxf(mx, __shfl_xor(mx, off));
                    float mnew  = fmaxf(m_run[mt][r], mx);
                    float alpha = __builtin_amdgcn_exp2f(m_run[mt][r] - mnew);
                    m_run[mt][r] = mnew;
                    lacc[mt][r] *= alpha;
#pragma unroll
                    for (int et = 0; et < 4; ++et)
                        oa[mt][et][r] *= alpha;
                }
        }

#pragma unroll
        for (int mt = 0; mt < 2; ++mt)
#pragma unroll
            for (int r = 0; r < 4; ++r) {
                int prow = (mt * 16 + lq * 4 + r) * 72;
#pragma unroll
                for (int nt = 0; nt < 4; ++nt) {
                    float pv = __builtin_amdgcn_exp2f(sc[mt][nt][r] - m_run[mt][r]);
                    Ps[wave][prow + nt * 16 + lm] = (__bf16)pv;
                }
            }

        asm volatile("s_waitcnt lgkmcnt(0)" ::: "memory");

#pragma unroll
        for (int ks = 0; ks < 2; ++ks) {
            bf16x8 aP[2];
#pragma unroll
            for (int mt = 0; mt < 2; ++mt)
                aP[mt] = *(const bf16x8*)&Ps[wave][(mt * 16 + lm) * 72
                                                  + ks * 32 + lq * 8];
#pragma unroll
            for (int mt = 0; mt < 2; ++mt)
                lacc[mt] = __builtin_amdgcn_mfma_f32_16x16x32_bf16(
                    aP[mt], vones, lacc[mt], 0, 0, 0);
#pragma unroll
            for (int et = 0; et < 4; ++et) {
                bf16x8 bV = *(const bf16x8*)((const char*)Vts[cur]
                    + (et * 16 + lm) * 128 + (((ks * 4 + lq) ^ (lm & 7)) * 16));
#pragma unroll
                for (int mt = 0; mt < 2; ++mt)
                    oa[mt][et] = __builtin_amdgcn_mfma_f32_16x16x32_bf16(
                        aP[mt], bV, oa[mt][et], 0, 0, 0);
            }
        }
        cur ^= 1;
    }

#pragma unroll
    for (int mt = 0; mt < 2; ++mt)
#pragma unroll
        for (int r = 0; r < 4; ++r) {
            float inv = 1.f / lacc[mt][r];
            size_t rowi = (size_t)(row0 + mt * 16 + lq * 4 + r) * DM + h * 64;
#pragma unroll
            for (int et = 0; et < 4; ++et)
                o[rowi + et * 16 + lm] = (__bf16)(oa[mt][et][r] * inv);
        }
}

// ---------------------------------------------------------------------------
extern "C" void kernel_launch(void* const* d_in, const int* in_sizes, int n_in,
                              void* d_out, int out_size, void* d_ws, size_t ws_size,
                              hipStream_t stream)
{
    const float* target = (const float*)d_in[0];
    const float* source = (const float*)d_in[1];
    const float* value  = (const float*)d_in[2];
    const float* Wq = (const float*)d_in[3];
    const float* bq = (const float*)d_in[4];
    const float* Wk = (const float*)d_in[5];
    const float* bk = (const float*)d_in[6];
    const float* Wv = (const float*)d_in[7];
    const float* bv = (const float*)d_in[8];
    const float* Wo = (const float*)d_in[9];
    const float* bo = (const float*)d_in[10];
    float* out = (float*)d_out;

    // ws layout (bytes):
    char* p = (char*)d_ws;
    __bf16* Tb  = (__bf16*)(p);              // target bf16   16,777,216 [ab alias]
    __bf16* Sb  = (__bf16*)(p + 16777216);   // source bf16    8,192,000
    __bf16* vtb = (__bf16*)(p + 16777216);   // V^T bf16 2,097,152 (aliases Sb,
                                             //  written by combine after QKV done)
    __bf16* kb  = (__bf16*)(p + 24969216);   // K proj bf16    2,048,000
    __bf16* WqT = (__bf16*)(p + 29065216);   // Wq^T bf16      2,097,152
    __bf16* WoT = (__bf16*)(p + 31162368);   // Wo^T bf16      8,388,608
    char*   R   =           p + 39550976;    // region 24,969,216
    __bf16* Vb  = (__bf16*)(R);              // value bf16     8,192,000
    __bf16* WvT = (__bf16*)(R + 8192000);    // Wv^T bf16      8,388,608
    __bf16* WkT = (__bf16*)(R + 16580608);   // Wk^T bf16      8,388,608
    // d_out (134 MB) doubles as scratch until the final O-proj overwrites it:
    __bf16* qb    = (__bf16*)d_out;                       // 16,777,216
    float*  kpart = (float*)((char*)d_out + 16777216);    // 4x1000x1024 f32 16,384,000
    float*  vpart = (float*)((char*)d_out + 33161216);    // 16,384,000
    __bf16* ab    = (__bf16*)(p);            // attn out (aliases Tb, dead by then)

    // 1. fused prep: casts + weight transposes (16192 + 3328 blocks)
    prep_kernel<<<19520, 256, 0, stream>>>(target, source, value, Wq, Wk, Wv, Wo,
                                           Tb, Sb, Vb, WqT, WkT, WvT, WoT);
    // 2. fused Q/K/V projections: 256 uniform fine-phase blocks, one round
    qkv_pipe_kernel<<<256, 512, 0, stream>>>(Tb, Sb, Vb, WqT, WkT, WvT,
                                             bq, qb, kpart, vpart);
    // 3. split-K combine: kb elementwise; vtb transposed+padded
    combine_kv_kernel<<<1256, 256, 0, stream>>>(kpart, vpart, bk, bv, kb, vtb);
    // 4. MFMA flash attention
    attn_mfma_kernel<<<dim3(8, 128), 256, 0, stream>>>(qb, kb, vtb, ab);
    // 5. output projection: fine-phase register-pipelined 256^2 kernel
    gemm_o_pipe_kernel<<<512, 512, 0, stream>>>(ab, WoT, bo, out);
}

// Round 6
// 444.658 us; speedup vs baseline: 1.0334x; 1.0319x over previous
//
#include <hip/hip_runtime.h>
#include <hip/hip_bf16.h>
#include <math.h>

#define B_SZ 8
#define L_SZ 1024
#define S_SZ 1000
#define DM   1024      // d_model = H*E = q/k/v row stride
#define DL   4096      // d_llm
#define NH   16
#define EH   64
#define QK_SCALE 0.180336880f   // (1/sqrt(64)) * log2(e): folded into Q projection
#define NT64 16                 // K-slice 1024 / BK 64

typedef __bf16 bf16x8 __attribute__((ext_vector_type(8)));
typedef __bf16 bf16x4 __attribute__((ext_vector_type(4)));
typedef float  f32x4  __attribute__((ext_vector_type(4)));

// async 16-byte global -> LDS (DMA, no VGPR round trip)
__device__ __forceinline__ void async16(const void* g, void* l) {
    __builtin_amdgcn_global_load_lds(
        (const __attribute__((address_space(1))) void*)g,
        (__attribute__((address_space(3))) void*)l, 16, 0, 0);
}

// ---------------------------------------------------------------------------
// fused prep: casts (bid<16192) + weight transposes (bid>=16192)
// ---------------------------------------------------------------------------
__global__ __launch_bounds__(256) void prep_kernel(
    const float* __restrict__ target, const float* __restrict__ source,
    const float* __restrict__ value,
    const float* __restrict__ Wq, const float* __restrict__ Wk,
    const float* __restrict__ Wv, const float* __restrict__ Wo,
    __bf16* __restrict__ Tb, __bf16* __restrict__ Sb, __bf16* __restrict__ Vb,
    __bf16* __restrict__ WqT, __bf16* __restrict__ WkT,
    __bf16* __restrict__ WvT, __bf16* __restrict__ WoT)
{
    __shared__ float t[64][68];
    int bid = blockIdx.x;
    if (bid < 16192) {
        const float* in; __bf16* out; int i;
        if (bid < 8192)       { in = target; out = Tb; i = bid * 256 + threadIdx.x; }
        else if (bid < 12192) { in = source; out = Sb; i = (bid - 8192)  * 256 + threadIdx.x; }
        else                  { in = value;  out = Vb; i = (bid - 12192) * 256 + threadIdx.x; }
        float4 x = ((const float4*)in)[i];
        bf16x4 y;
        y.x = (__bf16)x.x; y.y = (__bf16)x.y;
        y.z = (__bf16)x.z; y.w = (__bf16)x.w;
        ((bf16x4*)out)[i] = y;
        return;
    }
    bid -= 16192;
    const float* W; __bf16* WT; int K, N, bx, by;
    if (bid < 256)       { W = Wq; WT = WqT; K = DM; N = DM; int u = bid;        bx = u & 15; by = u >> 4; }
    else if (bid < 1280) { W = Wk; WT = WkT; K = DL; N = DM; int u = bid - 256;  bx = u & 15; by = u >> 4; }
    else if (bid < 2304) { W = Wv; WT = WvT; K = DL; N = DM; int u = bid - 1280; bx = u & 15; by = u >> 4; }
    else                 { W = Wo; WT = WoT; K = DM; N = DL; int u = bid - 2304; bx = u & 63; by = u >> 6; }
    const int k0 = by * 64, n0 = bx * 64;
    const int tx = threadIdx.x & 15, ty = threadIdx.x >> 4;

#pragma unroll
    for (int tt = 0; tt < 4; ++tt) {
        int r = ty + 16 * tt;
        float4 x = *(const float4*)&W[(size_t)(k0 + r) * N + n0 + 4 * tx];
        *(float4*)&t[r][4 * tx] = x;
    }
    __syncthreads();
#pragma unroll
    for (int tt = 0; tt < 4; ++tt) {
        int n = ty + 16 * tt;
        bf16x4 y;
        y.x = (__bf16)t[4 * tx + 0][n];
        y.y = (__bf16)t[4 * tx + 1][n];
        y.z = (__bf16)t[4 * tx + 2][n];
        y.w = (__bf16)t[4 * tx + 3][n];
        *(bf16x4*)&WT[(size_t)(n0 + n) * K + k0 + 4 * tx] = y;
    }
}

// ---------------------------------------------------------------------------
// m201-rhythm 256x256 GEMM body. BK=64, 512 thr = 8 waves (2M x 4N).
// LDS: 2 buffers x 2 kk-halves x 256x32 per operand = 128 KB.
// Per K-tile, 4 phases of 16 MFMA. Each phase:
//   {stage 1 column-half | ds_read this phase's frags | s_barrier |
//    lgkmcnt(0)+sched_barrier | setprio(1) 16 MFMA setprio(0) | s_barrier}
// Read latency is absorbed by the barrier wait (m201 mechanism).
// Stage schedule during tile t (all overwrite-after-consume safe):
//   ph1: A(t+1).kk1   ph2: B(t+1).kk1   [other buffer; data dead since t-1]
//   ph3: A(t+2).kk0   ph4: B(t+2).kk0   [own buffer; kk0 consumed at ph2 bar]
// Boundary (once/tile): vmcnt(4) -> oldest 8 of 12 outstanding land = ALL of
// tile t+1; keeps (t+2).kk0's 4 loads in flight (never 0 mid-loop).
// Prologue (12 loads + vmcnt(4)) enters the same invariant.
// omode 0: bf16 (acc+bias)*oscale | 1: f32 acc+bias | 2: f32 raw (split-K).
// ---------------------------------------------------------------------------
__device__ __forceinline__ void pipe_body(
    const __bf16* __restrict__ A, const __bf16* __restrict__ BT, int ld,
    const float* __restrict__ bias, void* __restrict__ Cv, int ldc,
    int M, int m0, int n0, float oscale, int omode,
    __bf16* sAb, __bf16* sBb)
{
    const int tid  = threadIdx.x;
    const int lane = tid & 63, wave = tid >> 6;
    const int wr = wave >> 2, wc = wave & 3;
    const int lm = lane & 15, lq = lane >> 4;

    f32x4 acc[8][4];
#pragma unroll
    for (int i = 0; i < 8; ++i)
#pragma unroll
        for (int j = 0; j < 4; ++j)
            acc[i][j] = (f32x4){0.f, 0.f, 0.f, 0.f};

    // stage one column-half (256 rows x 32 cols) of A or B: 2 loads/wave.
    // source pre-swizzled: slot s holds global seg s^(r&3)  (rule 21)
    auto stageA = [&](int buf, int kk, int t) {
        const int k0 = t * 64 + kk * 32;
        char* base = (char*)sAb + (buf * 2 + kk) * 16384;
#pragma unroll
        for (int i = 0; i < 2; ++i) {
            int cc = i * 512 + tid;            // 16B chunk: row cc>>2, slot cc&3
            int r = cc >> 2;
            int sg = (cc & 3) ^ (r & 3);
            int gm = m0 + r; if (gm >= M) gm = M - 1;
            async16(A + (size_t)gm * ld + k0 + sg * 8, base + cc * 16);
        }
    };
    auto stageB = [&](int buf, int kk, int t) {
        const int k0 = t * 64 + kk * 32;
        char* base = (char*)sBb + (buf * 2 + kk) * 16384;
#pragma unroll
        for (int i = 0; i < 2; ++i) {
            int cc = i * 512 + tid;
            int r = cc >> 2;
            int sg = (cc & 3) ^ (r & 3);
            async16(BT + (size_t)(n0 + r) * ld + k0 + sg * 8, base + cc * 16);
        }
    };

    bf16x8 fbk0[4], fbk1[4], fa[4];
    auto read_fb = [&](int buf, int kk, bf16x8 (&fb)[4]) {
        const char* base = (const char*)sBb + (buf * 2 + kk) * 16384;
#pragma unroll
        for (int ni = 0; ni < 4; ++ni) {
            int r = wc * 64 + ni * 16 + lm;
            fb[ni] = *(const bf16x8*)(base + r * 64 + ((lq ^ (r & 3)) * 16));
        }
    };
    auto read_fa = [&](int buf, int kk, int mo) {
        const char* base = (const char*)sAb + (buf * 2 + kk) * 16384;
#pragma unroll
        for (int i = 0; i < 4; ++i) {
            int r = wr * 128 + (mo + i) * 16 + lm;
            fa[i] = *(const bf16x8*)(base + r * 64 + ((lq ^ (r & 3)) * 16));
        }
    };
    auto mfma16 = [&](bf16x8 (&fb)[4], int mo) {
        __builtin_amdgcn_s_setprio(1);
#pragma unroll
        for (int i = 0; i < 4; ++i)
#pragma unroll
            for (int ni = 0; ni < 4; ++ni)
                acc[mo + i][ni] = __builtin_amdgcn_mfma_f32_16x16x32_bf16(
                    fa[i], fb[ni], acc[mo + i][ni], 0, 0, 0);
        __builtin_amdgcn_s_setprio(0);
    };

#define PHASE_SYNC() do { \
        __builtin_amdgcn_s_barrier(); \
        asm volatile("s_waitcnt lgkmcnt(0)" ::: "memory"); \
        __builtin_amdgcn_sched_barrier(0); } while (0)

    // prologue: tile0 (4 halves) + tile1 kk0 halves = 12 loads
    stageA(0, 0, 0); stageB(0, 0, 0); stageA(0, 1, 0); stageB(0, 1, 0);
    stageA(1, 0, 1); stageB(1, 0, 1);
    asm volatile("s_waitcnt vmcnt(4)" ::: "memory");   // tile0 landed, 4 in flight
    __builtin_amdgcn_sched_barrier(0);
    __builtin_amdgcn_s_barrier();

    for (int t = 0; t < NT64; ++t) {
        const int b = t & 1, bn = b ^ 1;
        // ph1: kk0 frags (fb + fa mi0-3) | stage A(t+1).kk1
        if (t + 1 < NT64) stageA(bn, 1, t + 1);
        read_fb(b, 0, fbk0);
        read_fa(b, 0, 0);
        PHASE_SYNC();
        mfma16(fbk0, 0);
        __builtin_amdgcn_s_barrier();
        // ph2: fa mi4-7 kk0 | stage B(t+1).kk1
        if (t + 1 < NT64) stageB(bn, 1, t + 1);
        read_fa(b, 0, 4);
        PHASE_SYNC();
        mfma16(fbk0, 4);
        __builtin_amdgcn_s_barrier();
        // ph3: kk1 frags (fb + fa mi0-3) | stage A(t+2).kk0
        if (t + 2 < NT64) stageA(b, 0, t + 2);
        read_fb(b, 1, fbk1);
        read_fa(b, 1, 0);
        PHASE_SYNC();
        mfma16(fbk1, 0);
        __builtin_amdgcn_s_barrier();
        // ph4: fa mi4-7 kk1 | stage B(t+2).kk0
        if (t + 2 < NT64) stageB(b, 0, t + 2);
        read_fa(b, 1, 4);
        PHASE_SYNC();
        mfma16(fbk1, 4);
        // tile boundary: land ALL of tile t+1, keep (t+2).kk0 in flight
        if (t + 2 < NT64)
            asm volatile("s_waitcnt vmcnt(4)" ::: "memory");
        else
            asm volatile("s_waitcnt vmcnt(0)" ::: "memory");
        __builtin_amdgcn_sched_barrier(0);
        __builtin_amdgcn_s_barrier();
    }
#undef PHASE_SYNC

    // epilogue
#pragma unroll
    for (int mi = 0; mi < 8; ++mi) {
        int gm0 = m0 + wr * 128 + mi * 16 + lq * 4;
#pragma unroll
        for (int ni = 0; ni < 4; ++ni) {
            int gn = n0 + wc * 64 + ni * 16 + lm;
            float bv = (omode == 2) ? 0.f : bias[gn];
#pragma unroll
            for (int r = 0; r < 4; ++r) {
                int gm = gm0 + r;
                if (gm < M) {
                    float val = acc[mi][ni][r] + bv;
                    if (omode == 0)
                        ((__bf16*)Cv)[(size_t)gm * ldc + gn] = (__bf16)(val * oscale);
                    else
                        ((float*)Cv)[(size_t)gm * ldc + gn] = val;
                }
            }
        }
    }
}

// ---------------------------------------------------------------------------
// fused Q/K/V projection: 256 blocks, one wave-round, uniform Kslice=1024.
//  bid [0,128):   Q   (M=8192, 32x4 tiles)          -> qb   (bf16, QK_SCALE)
//  bid [128,192): K   split-K x4, 4x4 tiles, M=1000 -> kpart (f32 raw)
//  bid [192,256): V   split-K x4                    -> vpart (f32 raw)
// ---------------------------------------------------------------------------
__global__ __launch_bounds__(512, 2) void qkv_pipe_kernel(
    const __bf16* __restrict__ Tb, const __bf16* __restrict__ Sb,
    const __bf16* __restrict__ Vb,
    const __bf16* __restrict__ WqT, const __bf16* __restrict__ WkT,
    const __bf16* __restrict__ WvT,
    const float* __restrict__ bq,
    __bf16* __restrict__ qb, float* __restrict__ kpart, float* __restrict__ vpart)
{
    __shared__ __bf16 sA[2][2][256 * 32];
    __shared__ __bf16 sB[2][2][256 * 32];
    int bid = blockIdx.x;
    const __bf16 *A, *BT; const float* bias; void* Cv;
    int ld, M, m0, n0, omode; float osc;
    if (bid < 128) {
        A = Tb; BT = WqT; bias = bq; Cv = qb; ld = DM; M = B_SZ * L_SZ;
        m0 = (bid >> 2) * 256; n0 = (bid & 3) * 256; omode = 0; osc = QK_SCALE;
    } else if (bid < 192) {
        int u = bid - 128, ks = u >> 4, v = u & 15;
        A = Sb + ks * 1024; BT = WkT + ks * 1024; bias = nullptr;
        Cv = kpart + (size_t)ks * 1024000; ld = DL; M = S_SZ;
        m0 = (v >> 2) * 256; n0 = (v & 3) * 256; omode = 2; osc = 1.f;
    } else {
        int u = bid - 192, ks = u >> 4, v = u & 15;
        A = Vb + ks * 1024; BT = WvT + ks * 1024; bias = nullptr;
        Cv = vpart + (size_t)ks * 1024000; ld = DL; M = S_SZ;
        m0 = (v >> 2) * 256; n0 = (v & 3) * 256; omode = 2; osc = 1.f;
    }
    pipe_body(A, BT, ld, bias, Cv, DM, M, m0, n0, osc, omode,
              &sA[0][0][0], &sB[0][0][0]);
}

// ---------------------------------------------------------------------------
// O-projection: same pipe body, 512 blocks (2 rounds), f32 out + bias.
// ---------------------------------------------------------------------------
__global__ __launch_bounds__(512, 2) void gemm_o_pipe_kernel(
    const __bf16* __restrict__ ab, const __bf16* __restrict__ WoT,
    const float* __restrict__ bo, float* __restrict__ out)
{
    __shared__ __bf16 sA[2][2][256 * 32];
    __shared__ __bf16 sB[2][2][256 * 32];
    int bid = blockIdx.x;
    bid = (bid & 7) * 64 + (bid >> 3);             // XCD swizzle (512%8==0)
    pipe_body(ab, WoT, DM, bo, out, DL, B_SZ * L_SZ,
              (bid >> 4) * 256, (bid & 15) * 256, 1.f, 1,
              &sA[0][0][0], &sB[0][0][0]);
}

// ---------------------------------------------------------------------------
// split-K combine:
//  bid [0,1000): kb[s][d] = bf16(sum_j kpart[j] + bk)           (elementwise)
//  bid [1000,1256): vtb[d][s] = bf16(sum_j vpart[j] + bv), transposed 64x64
//                   tile, zero-padded for s >= 1000.
// ---------------------------------------------------------------------------
__global__ __launch_bounds__(256) void combine_kv_kernel(
    const float* __restrict__ kpart, const float* __restrict__ vpart,
    const float* __restrict__ bk, const float* __restrict__ bv,
    __bf16* __restrict__ kb, __bf16* __restrict__ vtb)
{
    __shared__ float t[64][68];
    const int bid = blockIdx.x, tid = threadIdx.x;
    if (bid < 1000) {
        int e4 = bid * 256 + tid;
        int col = (e4 & 255) * 4;
        float4 s = *(const float4*)&bk[col];
#pragma unroll
        for (int j = 0; j < 4; ++j) {
            float4 pp = *(const float4*)&kpart[(size_t)j * 1024000 + (size_t)e4 * 4];
            s.x += pp.x; s.y += pp.y; s.z += pp.z; s.w += pp.w;
        }
        bf16x4 y;
        y.x = (__bf16)s.x; y.y = (__bf16)s.y;
        y.z = (__bf16)s.z; y.w = (__bf16)s.w;
        ((bf16x4*)kb)[e4] = y;
    } else {
        int u = bid - 1000;
        int d0 = (u & 15) * 64, s0 = (u >> 4) * 64;
#pragma unroll
        for (int tt = 0; tt < 4; ++tt) {
            int idx = tt * 256 + tid;
            int r = idx >> 4, c4 = idx & 15;
            float4 s = {0.f, 0.f, 0.f, 0.f};
            if (s0 + r < S_SZ) {
                s = *(const float4*)&bv[d0 + c4 * 4];
#pragma unroll
                for (int j = 0; j < 4; ++j) {
                    float4 pp = *(const float4*)&vpart[(size_t)j * 1024000
                                + (size_t)(s0 + r) * 1024 + d0 + c4 * 4];
                    s.x += pp.x; s.y += pp.y; s.z += pp.z; s.w += pp.w;
                }
            }
            *(float4*)&t[r][c4 * 4] = s;
        }
        __syncthreads();
#pragma unroll
        for (int tt = 0; tt < 2; ++tt) {
            int idx = tt * 256 + tid;
            int d = idx >> 3, ch = idx & 7;
            bf16x8 o;
#pragma unroll
            for (int j = 0; j < 8; ++j) o[j] = (__bf16)t[ch * 8 + j][d];
            *(bf16x8*)&vtb[(size_t)(d0 + d) * 1024 + s0 + ch * 8] = o;
        }
    }
}

// ---------------------------------------------------------------------------
// MFMA flash attention (unchanged).
// ---------------------------------------------------------------------------
__global__ __launch_bounds__(256) void attn_mfma_kernel(
    const __bf16* __restrict__ q,   // (B*L, DM), pre-scaled
    const __bf16* __restrict__ k,   // (S, DM)
    const __bf16* __restrict__ vt,  // (DM, 1024) zero-padded s>=S
    __bf16* __restrict__ o)         // (B*L, DM)
{
    __shared__ __bf16 Ks [2][64 * 64];
    __shared__ __bf16 Vts[2][64 * 64];
    __shared__ __bf16 Ps [4][32 * 72];

    const int tid  = threadIdx.x;
    const int lane = tid & 63;
    const int wave = tid >> 6;
    const int lm   = lane & 15;
    const int lq   = lane >> 4;
    const int bh = blockIdx.y;
    const int b  = bh >> 4;
    const int h  = bh & 15;
    const int l0 = blockIdx.x * 128;
    const int row0 = b * L_SZ + l0 + wave * 32;

    bf16x8 qf[2][2];
#pragma unroll
    for (int mt = 0; mt < 2; ++mt)
#pragma unroll
        for (int ks = 0; ks < 2; ++ks)
            qf[mt][ks] = *(const bf16x8*)&q[(size_t)(row0 + mt * 16 + lm) * DM
                                           + h * 64 + ks * 32 + lq * 8];

    f32x4 oa[2][4];
    f32x4 lacc[2];
    float m_run[2][4];
#pragma unroll
    for (int mt = 0; mt < 2; ++mt) {
        lacc[mt] = (f32x4){0.f, 0.f, 0.f, 0.f};
#pragma unroll
        for (int r = 0; r < 4; ++r) m_run[mt][r] = -1e30f;
#pragma unroll
        for (int et = 0; et < 4; ++et) oa[mt][et] = (f32x4){0.f, 0.f, 0.f, 0.f};
    }

    bf16x8 vones;
#pragma unroll
    for (int j = 0; j < 8; ++j) vones[j] = (__bf16)1.0f;

    auto stage = [&](int bi, int s0v) {
#pragma unroll
        for (int t = 0; t < 2; ++t) {
            int cc = t * 256 + tid;
            int r = cc >> 3, segL = cc & 7;
            int segG = segL ^ (r & 7);
            int sg = s0v + r; if (sg >= S_SZ) sg = S_SZ - 1;
            async16(k  + (size_t)sg * DM + h * 64 + segG * 8,
                    (char*)Ks[bi] + cc * 16);
            async16(vt + (size_t)(h * 64 + r) * 1024 + s0v + segG * 8,
                    (char*)Vts[bi] + cc * 16);
        }
    };

    stage(0, 0);
    int cur = 0;

    for (int s0 = 0; s0 < S_SZ; s0 += 64) {
        __syncthreads();
        if (s0 + 64 < S_SZ) stage(cur ^ 1, s0 + 64);

        f32x4 sc[2][4];
#pragma unroll
        for (int mt = 0; mt < 2; ++mt)
#pragma unroll
            for (int nt = 0; nt < 4; ++nt)
                sc[mt][nt] = (f32x4){0.f, 0.f, 0.f, 0.f};
#pragma unroll
        for (int ks = 0; ks < 2; ++ks)
#pragma unroll
            for (int nt = 0; nt < 4; ++nt) {
                bf16x8 bK = *(const bf16x8*)((const char*)Ks[cur]
                    + (nt * 16 + lm) * 128 + (((ks * 4 + lq) ^ (lm & 7)) * 16));
#pragma unroll
                for (int mt = 0; mt < 2; ++mt)
                    sc[mt][nt] = __builtin_amdgcn_mfma_f32_16x16x32_bf16(
                        qf[mt][ks], bK, sc[mt][nt], 0, 0, 0);
            }

        if (s0 + 64 > S_SZ) {
#pragma unroll
            for (int nt = 0; nt < 4; ++nt) {
                bool masked = (s0 + nt * 16 + lm >= S_SZ);
                if (masked)
#pragma unroll
                    for (int mt = 0; mt < 2; ++mt)
#pragma unroll
                        for (int r = 0; r < 4; ++r) sc[mt][nt][r] = -1e30f;
            }
        }

        float pm[2][4];
        bool ok = true;
#pragma unroll
        for (int mt = 0; mt < 2; ++mt)
#pragma unroll
            for (int r = 0; r < 4; ++r) {
                pm[mt][r] = fmaxf(fmaxf(sc[mt][0][r], sc[mt][1][r]),
                                  fmaxf(sc[mt][2][r], sc[mt][3][r]));
                ok = ok && (pm[mt][r] <= m_run[mt][r] + 8.f);
            }
        if (!__all((int)ok)) {
#pragma unroll
            for (int mt = 0; mt < 2; ++mt)
#pragma unroll
                for (int r = 0; r < 4; ++r) {
                    float mx = pm[mt][r];
#pragma unroll
                    for (int off = 1; off < 16; off <<= 1)
                        mx = fmaxf(mx, __shfl_xor(mx, off));
                    float mnew  = fmaxf(m_run[mt][r], mx);
                    float alpha = __builtin_amdgcn_exp2f(m_run[mt][r] - mnew);
                    m_run[mt][r] = mnew;
                    lacc[mt][r] *= alpha;
#pragma unroll
                    for (int et = 0; et < 4; ++et)
                        oa[mt][et][r] *= alpha;
                }
        }

#pragma unroll
        for (int mt = 0; mt < 2; ++mt)
#pragma unroll
            for (int r = 0; r < 4; ++r) {
                int prow = (mt * 16 + lq * 4 + r) * 72;
#pragma unroll
                for (int nt = 0; nt < 4; ++nt) {
                    float pv = __builtin_amdgcn_exp2f(sc[mt][nt][r] - m_run[mt][r]);
                    Ps[wave][prow + nt * 16 + lm] = (__bf16)pv;
                }
            }

        asm volatile("s_waitcnt lgkmcnt(0)" ::: "memory");

#pragma unroll
        for (int ks = 0; ks < 2; ++ks) {
            bf16x8 aP[2];
#pragma unroll
            for (int mt = 0; mt < 2; ++mt)
                aP[mt] = *(const bf16x8*)&Ps[wave][(mt * 16 + lm) * 72
                                                  + ks * 32 + lq * 8];
#pragma unroll
            for (int mt = 0; mt < 2; ++mt)
                lacc[mt] = __builtin_amdgcn_mfma_f32_16x16x32_bf16(
                    aP[mt], vones, lacc[mt], 0, 0, 0);
#pragma unroll
            for (int et = 0; et < 4; ++et) {
                bf16x8 bV = *(const bf16x8*)((const char*)Vts[cur]
                    + (et * 16 + lm) * 128 + (((ks * 4 + lq) ^ (lm & 7)) * 16));
#pragma unroll
                for (int mt = 0; mt < 2; ++mt)
                    oa[mt][et] = __builtin_amdgcn_mfma_f32_16x16x32_bf16(
                        aP[mt], bV, oa[mt][et], 0, 0, 0);
            }
        }
        cur ^= 1;
    }

#pragma unroll
    for (int mt = 0; mt < 2; ++mt)
#pragma unroll
        for (int r = 0; r < 4; ++r) {
            float inv = 1.f / lacc[mt][r];
            size_t rowi = (size_t)(row0 + mt * 16 + lq * 4 + r) * DM + h * 64;
#pragma unroll
            for (int et = 0; et < 4; ++et)
                o[rowi + et * 16 + lm] = (__bf16)(oa[mt][et][r] * inv);
        }
}

// ---------------------------------------------------------------------------
extern "C" void kernel_launch(void* const* d_in, const int* in_sizes, int n_in,
                              void* d_out, int out_size, void* d_ws, size_t ws_size,
                              hipStream_t stream)
{
    const float* target = (const float*)d_in[0];
    const float* source = (const float*)d_in[1];
    const float* value  = (const float*)d_in[2];
    const float* Wq = (const float*)d_in[3];
    const float* bq = (const float*)d_in[4];
    const float* Wk = (const float*)d_in[5];
    const float* bk = (const float*)d_in[6];
    const float* Wv = (const float*)d_in[7];
    const float* bv = (const float*)d_in[8];
    const float* Wo = (const float*)d_in[9];
    const float* bo = (const float*)d_in[10];
    float* out = (float*)d_out;

    // ws layout (bytes):
    char* p = (char*)d_ws;
    __bf16* Tb  = (__bf16*)(p);              // target bf16   16,777,216 [ab alias]
    __bf16* Sb  = (__bf16*)(p + 16777216);   // source bf16    8,192,000
    __bf16* vtb = (__bf16*)(p + 16777216);   // V^T bf16 2,097,152 (aliases Sb,
                                             //  written by combine after QKV done)
    __bf16* kb  = (__bf16*)(p + 24969216);   // K proj bf16    2,048,000
    __bf16* WqT = (__bf16*)(p + 29065216);   // Wq^T bf16      2,097,152
    __bf16* WoT = (__bf16*)(p + 31162368);   // Wo^T bf16      8,388,608
    char*   R   =           p + 39550976;    // region 24,969,216
    __bf16* Vb  = (__bf16*)(R);              // value bf16     8,192,000
    __bf16* WvT = (__bf16*)(R + 8192000);    // Wv^T bf16      8,388,608
    __bf16* WkT = (__bf16*)(R + 16580608);   // Wk^T bf16      8,388,608
    // d_out (134 MB) doubles as scratch until the final O-proj overwrites it:
    __bf16* qb    = (__bf16*)d_out;                       // 16,777,216
    float*  kpart = (float*)((char*)d_out + 16777216);    // 4x1000x1024 f32 16,384,000
    float*  vpart = (float*)((char*)d_out + 33161216);    // 16,384,000
    __bf16* ab    = (__bf16*)(p);            // attn out (aliases Tb, dead by then)

    // 1. fused prep: casts + weight transposes (16192 + 3328 blocks)
    prep_kernel<<<19520, 256, 0, stream>>>(target, source, value, Wq, Wk, Wv, Wo,
                                           Tb, Sb, Vb, WqT, WkT, WvT, WoT);
    // 2. fused Q/K/V projections: 256 uniform m201-rhythm blocks, one round
    qkv_pipe_kernel<<<256, 512, 0, stream>>>(Tb, Sb, Vb, WqT, WkT, WvT,
                                             bq, qb, kpart, vpart);
    // 3. split-K combine: kb elementwise; vtb transposed+padded
    combine_kv_kernel<<<1256, 256, 0, stream>>>(kpart, vpart, bk, bv, kb, vtb);
    // 4. MFMA flash attention
    attn_mfma_kernel<<<dim3(8, 128), 256, 0, stream>>>(qb, kb, vtb, ab);
    // 5. output projection: m201-rhythm 256^2 kernel
    gemm_o_pipe_kernel<<<512, 512, 0, stream>>>(ab, WoT, bo, out);
}